// Round 5
// baseline (390.823 us; speedup 1.0000x reference)
//
#include <hip/hip_runtime.h>

#define HDIM 128
#define NGRAPH 64
#define NCLASS 7
#define PG_NODES 192  // nodes per k_pgemm block (3 sub-chunks of 64)

// ---------------- W2 transpose (once, 64 KB; no dependencies, launched early) ----------------

__global__ void k_wtr(const float* __restrict__ W, float* __restrict__ WT) {
  int idx = blockIdx.x * 256 + threadIdx.x;  // grid 64 -> 16384
  int c = idx >> 7, k = idx & 127;
  WT[idx] = W[k * 128 + c];
}

// ---------------- setup: in-degree, dinv, dst-CSR ----------------

__global__ void k_count(const int* __restrict__ col, int E, int* __restrict__ deg) {
  int e = blockIdx.x * blockDim.x + threadIdx.x;
  if (e < E) atomicAdd(&deg[col[e]], 1);
}

// exclusive scan of deg -> off; also emits dinv = rsqrt(deg+1)
__global__ void k_scan1(const int* __restrict__ in, int n, int* __restrict__ outLocal,
                        int* __restrict__ tileSums, float* __restrict__ dinv) {
  __shared__ int sh[256];
  int t = threadIdx.x;
  int base = blockIdx.x * 1024 + t * 4;
  int v[4], sum = 0;
#pragma unroll
  for (int j = 0; j < 4; j++) {
    int idx = base + j;
    int x = (idx < n) ? in[idx] : 0;
    if (idx < n) dinv[idx] = rsqrtf((float)(x + 1));  // +1 self-loop
    v[j] = sum; sum += x;
  }
  sh[t] = sum; __syncthreads();
  for (int o = 1; o < 256; o <<= 1) {
    int val = (t >= o) ? sh[t - o] : 0;
    __syncthreads();
    sh[t] += val;
    __syncthreads();
  }
  int excl = (t == 0) ? 0 : sh[t - 1];
  if (t == 255) tileSums[blockIdx.x] = sh[255];
#pragma unroll
  for (int j = 0; j < 4; j++) {
    int idx = base + j;
    if (idx < n) outLocal[idx] = excl + v[j];
  }
}

__global__ void k_scan2(int* __restrict__ tileSums, int numTiles) {
  __shared__ int sh[128];
  int t = threadIdx.x;
  sh[t] = (t < numTiles) ? tileSums[t] : 0;
  __syncthreads();
  for (int o = 1; o < 128; o <<= 1) {
    int val = (t >= o) ? sh[t - o] : 0;
    __syncthreads();
    sh[t] += val;
    __syncthreads();
  }
  if (t < numTiles) tileSums[t] = (t == 0) ? 0 : sh[t - 1];
}

__global__ void k_scan3(int* __restrict__ off, const int* __restrict__ tileSums, int n, int E) {
  int i = blockIdx.x * blockDim.x + threadIdx.x;
  if (i < n) off[i] += tileSums[i >> 10];
  if (i == 0) off[n] = E;
}

// ---------------- fused edge pass: CSR build + layer-1 scalar aggregation ----------------
// CSR payload packed (src, w) into int2 (one 8B scattered store instead of two 4B).
// s[dst] accumulated with native fp32 atomics (400 KB target -> L2-resident).

__global__ void k_edge(const int* __restrict__ row, const int* __restrict__ col, int E,
                       const int* __restrict__ off, int* __restrict__ cursor,
                       const float* __restrict__ dinv, const float* __restrict__ x,
                       float* __restrict__ s, int2* __restrict__ gw, int n) {
  int e = blockIdx.x * blockDim.x + threadIdx.x;
  if (e < E) {
    int r = row[e], c = col[e];
    float w = dinv[r] * dinv[c];
    int pos = off[c] + atomicAdd(&cursor[c], 1);
    gw[pos] = make_int2(r, __float_as_int(w));
    unsafeAtomicAdd(&s[c], w * x[r]);
  } else if (e - E < n) {
    int i = e - E;
    float d = dinv[i];
    unsafeAtomicAdd(&s[i], d * d * x[i]);  // self-loop term
  }
}

// ---------------- fused: h1 = relu(s*W1+b1) recomputed per edge + agg2 ----------------

__global__ void __launch_bounds__(256) k_l2in(const float* __restrict__ s,
                                              const int* __restrict__ off,
                                              const int2* __restrict__ gw,
                                              const float* __restrict__ dinv,
                                              const float* __restrict__ W1,
                                              const float* __restrict__ b1,
                                              float2* __restrict__ z, int n) {
  int node = blockIdx.x * 4 + (threadIdx.x >> 6);
  if (node >= n) return;
  int l = threadIdx.x & 63;
  float2 w1 = ((const float2*)W1)[l];
  float2 bv = ((const float2*)b1)[l];
  float di = dinv[node];
  float nself = di * di;
  float sv = s[node];
  float2 acc;
  acc.x = nself * fmaxf(fmaf(sv, w1.x, bv.x), 0.f);
  acc.y = nself * fmaxf(fmaf(sv, w1.y, bv.y), 0.f);
  int e0 = off[node], e1 = off[node + 1];
  int e = e0;
  for (; e + 4 <= e1; e += 4) {
    int2 p0 = gw[e], p1 = gw[e + 1], p2 = gw[e + 2], p3 = gw[e + 3];
    float s0 = s[p0.x], s1 = s[p1.x], s2 = s[p2.x], s3 = s[p3.x];
    float u0 = __int_as_float(p0.y), u1 = __int_as_float(p1.y);
    float u2 = __int_as_float(p2.y), u3 = __int_as_float(p3.y);
    acc.x = fmaf(u0, fmaxf(fmaf(s0, w1.x, bv.x), 0.f), acc.x);
    acc.y = fmaf(u0, fmaxf(fmaf(s0, w1.y, bv.y), 0.f), acc.y);
    acc.x = fmaf(u1, fmaxf(fmaf(s1, w1.x, bv.x), 0.f), acc.x);
    acc.y = fmaf(u1, fmaxf(fmaf(s1, w1.y, bv.y), 0.f), acc.y);
    acc.x = fmaf(u2, fmaxf(fmaf(s2, w1.x, bv.x), 0.f), acc.x);
    acc.y = fmaf(u2, fmaxf(fmaf(s2, w1.y, bv.y), 0.f), acc.y);
    acc.x = fmaf(u3, fmaxf(fmaf(s3, w1.x, bv.x), 0.f), acc.x);
    acc.y = fmaf(u3, fmaxf(fmaf(s3, w1.y, bv.y), 0.f), acc.y);
  }
  for (; e < e1; e++) {
    int2 p = gw[e];
    float ss = s[p.x];
    float w = __int_as_float(p.y);
    acc.x = fmaf(w, fmaxf(fmaf(ss, w1.x, bv.x), 0.f), acc.x);
    acc.y = fmaf(w, fmaxf(fmaf(ss, w1.y, bv.y), 0.f), acc.y);
  }
  z[(size_t)node * 64 + l] = acc;
}

// ---------------- GEMM: (n x 128) @ (128 x 128) + bias + relu ----------------
// 128x128 block tile, 256 threads, 8x8 thread tile, K chunked at 32.
// f = 0.5 B/FLOP of LDS traffic (vs 1.0 before) -> VALU/LDS co-limited.
// Both operands staged k-major (float4 along k) with XOR-on-k-quad swizzle:
//   slot(row,kq) = row*8 + (kq ^ ((row>>3)&7))
// Compute A-read: 4 addrs/instr in 4 distinct bank groups (free).
// Compute W-read: 16 addrs/instr, 2 per bank group (2-way = free).
// W2 is pre-transposed (k_wtr) so W staging is coalesced b128.

__global__ void __launch_bounds__(256, 3)
k_gemm(const float* __restrict__ A, const float* __restrict__ WT,
       const float* __restrict__ bias, float* __restrict__ out, int n) {
  __shared__ float4 As4[128 * 8];  // 16 KB
  __shared__ float4 Wt4[128 * 8];  // 16 KB
  const int t = threadIdx.x;
  const int tr = t >> 4;   // 0..15 row group (8 rows each)
  const int tc = t & 15;   // 0..15 col group (8 cols each)
  const int sa = tr & 7;
  const int sw = tc & 7;
  const int rowBase = blockIdx.x << 7;

  float acc[8][8] = {};

  for (int ch = 0; ch < 4; ch++) {
    const int kOff = ch << 5;
    __syncthreads();
    for (int l = t; l < 1024; l += 256) {
      int r = l >> 3, kq = l & 7;
      int grow = rowBase + r;
      float4 v = (grow < n) ? *(const float4*)&A[(size_t)grow * 128 + kOff + (kq << 2)]
                            : make_float4(0.f, 0.f, 0.f, 0.f);
      As4[(r << 3) + (kq ^ ((r >> 3) & 7))] = v;
    }
    for (int l = t; l < 1024; l += 256) {
      int c = l >> 3, kq = l & 7;
      float4 v = *(const float4*)&WT[(size_t)c * 128 + kOff + (kq << 2)];
      Wt4[(c << 3) + (kq ^ ((c >> 3) & 7))] = v;
    }
    __syncthreads();

    for (int kq = 0; kq < 8; kq++) {
      const int ka = kq ^ sa;
      const int kw = kq ^ sw;
      float4 a[8];
#pragma unroll
      for (int i = 0; i < 8; i++) a[i] = As4[(tr << 6) + (i << 3) + ka];
#pragma unroll
      for (int j = 0; j < 8; j++) {
        float4 w = Wt4[(tc << 6) + (j << 3) + kw];
#pragma unroll
        for (int i = 0; i < 8; i++) {
          float v = acc[i][j];
          v = fmaf(a[i].x, w.x, v);
          v = fmaf(a[i].y, w.y, v);
          v = fmaf(a[i].z, w.z, v);
          v = fmaf(a[i].w, w.w, v);
          acc[i][j] = v;
        }
      }
    }
  }

  const float4 b0 = *(const float4*)&bias[(tc << 3)];
  const float4 b1v = *(const float4*)&bias[(tc << 3) + 4];
#pragma unroll
  for (int i = 0; i < 8; i++) {
    int grow = rowBase + (tr << 3) + i;
    if (grow < n) {
      float4 o0, o1;
      o0.x = fmaxf(acc[i][0] + b0.x, 0.f);
      o0.y = fmaxf(acc[i][1] + b0.y, 0.f);
      o0.z = fmaxf(acc[i][2] + b0.z, 0.f);
      o0.w = fmaxf(acc[i][3] + b0.w, 0.f);
      o1.x = fmaxf(acc[i][4] + b1v.x, 0.f);
      o1.y = fmaxf(acc[i][5] + b1v.y, 0.f);
      o1.z = fmaxf(acc[i][6] + b1v.z, 0.f);
      o1.w = fmaxf(acc[i][7] + b1v.w, 0.f);
      *(float4*)&out[(size_t)grow * 128 + (tc << 3)] = o0;
      *(float4*)&out[(size_t)grow * 128 + (tc << 3) + 4] = o1;
    }
  }
}

// ---------------- layer 3 + pool as dense P^T * H ----------------

__global__ void k_pbuild(const int* __restrict__ row, const int* __restrict__ col, int E,
                         const float* __restrict__ dinv, const int* __restrict__ batch,
                         float* __restrict__ P, int n) {
  int e = blockIdx.x * blockDim.x + threadIdx.x;
  if (e < E) {
    int r = row[e], c = col[e];
    unsafeAtomicAdd(&P[(size_t)r * NGRAPH + batch[c]], dinv[r] * dinv[c]);
  } else if (e - E < n) {
    int i = e - E;
    float d = dinv[i];
    unsafeAtomicAdd(&P[(size_t)i * NGRAPH + batch[i]], d * d);
  }
}

__global__ void __launch_bounds__(256) k_pgemm(const float* __restrict__ H,
                                               const float* __restrict__ P,
                                               float* __restrict__ partials, int n) {
  __shared__ float4 Hl4[64 * 32];  // [i][j-quad]
  __shared__ float4 Pl4[64 * 16];  // [i][g-quad]
  const int t = threadIdx.x;
  const int jl = t & 31;
  const int gq = (t >> 5) << 1;
  float4 acc[8];
#pragma unroll
  for (int i = 0; i < 8; i++) acc[i] = make_float4(0.f, 0.f, 0.f, 0.f);
  const int base0 = blockIdx.x * PG_NODES;

  for (int sub = 0; sub < PG_NODES / 64; sub++) {
    const int base = base0 + sub * 64;
    __syncthreads();
    for (int l = t; l < 2048; l += 256) {
      int i = l >> 5, q = l & 31;
      int node = base + i;
      Hl4[l] = (node < n) ? *(const float4*)&H[(size_t)node * 128 + (q << 2)]
                          : make_float4(0.f, 0.f, 0.f, 0.f);
    }
    for (int l = t; l < 1024; l += 256) {
      int i = l >> 4, q = l & 15;
      int node = base + i;
      Pl4[l] = (node < n) ? *(const float4*)&P[(size_t)node * NGRAPH + (q << 2)]
                          : make_float4(0.f, 0.f, 0.f, 0.f);
    }
    __syncthreads();

#define FMA4(A, PV) \
  A.x = fmaf(PV, hv.x, A.x); A.y = fmaf(PV, hv.y, A.y); \
  A.z = fmaf(PV, hv.z, A.z); A.w = fmaf(PV, hv.w, A.w);
#pragma unroll 4
    for (int i = 0; i < 64; i++) {
      float4 hv = Hl4[i * 32 + jl];
      float4 pa = Pl4[i * 16 + gq];
      float4 pb = Pl4[i * 16 + gq + 1];
      FMA4(acc[0], pa.x) FMA4(acc[1], pa.y) FMA4(acc[2], pa.z) FMA4(acc[3], pa.w)
      FMA4(acc[4], pb.x) FMA4(acc[5], pb.y) FMA4(acc[6], pb.z) FMA4(acc[7], pb.w)
    }
#undef FMA4
  }

  float* dst = &partials[(size_t)blockIdx.x * (NGRAPH * HDIM)];
  int gb = (t >> 5) << 3;
#pragma unroll
  for (int gi = 0; gi < 8; gi++)
    *(float4*)&dst[(gb + gi) * HDIM + (jl << 2)] = acc[gi];
}

__global__ void k_reduce(const float* __restrict__ partials, float* __restrict__ pooled,
                         int nparts) {
  int cell = blockIdx.x * 256 + threadIdx.x;
  int stride = gridDim.y;
  int p = blockIdx.y;
  float a0 = 0.f, a1 = 0.f, a2 = 0.f, a3 = 0.f;
  for (; p + 3 * stride < nparts; p += 4 * stride) {
    a0 += partials[(size_t)p * 8192 + cell];
    a1 += partials[(size_t)(p + stride) * 8192 + cell];
    a2 += partials[(size_t)(p + 2 * stride) * 8192 + cell];
    a3 += partials[(size_t)(p + 3 * stride) * 8192 + cell];
  }
  for (; p < nparts; p += stride) a0 += partials[(size_t)p * 8192 + cell];
  unsafeAtomicAdd(&pooled[cell], (a0 + a1) + (a2 + a3));
}

// t1[g][j] = (pooledSum[g] . W3[:,j]) / cnt[g] + b3[j]; cnt via binary search (batch sorted)
__global__ void k_mid(const float* __restrict__ pooled, const int* __restrict__ batch, int n,
                      const float* __restrict__ W3, const float* __restrict__ b3,
                      float* __restrict__ t1) {
  __shared__ float invSh;
  int g = blockIdx.x, j = threadIdx.x;
  if (j == 0) {
    int lo = 0, hi = n;
    while (lo < hi) { int m = (lo + hi) >> 1; if (batch[m] < g) lo = m + 1; else hi = m; }
    int a = lo;
    lo = 0; hi = n;
    while (lo < hi) { int m = (lo + hi) >> 1; if (batch[m] < g + 1) lo = m + 1; else hi = m; }
    invSh = 1.f / fmaxf((float)(lo - a), 1.f);
  }
  __syncthreads();
  float inv = invSh;
  float acc = 0.f;
  for (int k = 0; k < HDIM; k++) acc = fmaf(pooled[g * HDIM + k], W3[k * HDIM + j], acc);
  t1[g * HDIM + j] = acc * inv + b3[j];
}

__global__ void k_out(const float* __restrict__ t1, const float* __restrict__ Wl,
                      const float* __restrict__ bl, float* __restrict__ out) {
  int t = threadIdx.x;
  int g = t >> 3, c = t & 7;
  if (g >= NGRAPH || c >= NCLASS) return;
  float acc = 0.f;
  for (int k = 0; k < HDIM; k++) acc = fmaf(t1[g * HDIM + k], Wl[k * NCLASS + c], acc);
  out[g * NCLASS + c] = acc + bl[c];
}

// ---------------- host ----------------

extern "C" void kernel_launch(void* const* d_in, const int* in_sizes, int n_in,
                              void* d_out, int out_size, void* d_ws, size_t ws_size,
                              hipStream_t stream) {
  const float* x   = (const float*)d_in[0];
  const int*   ei  = (const int*)d_in[1];
  const int*   bat = (const int*)d_in[2];
  const float* W1  = (const float*)d_in[3];
  const float* b1  = (const float*)d_in[4];
  const float* W2  = (const float*)d_in[5];
  const float* b2  = (const float*)d_in[6];
  const float* W3  = (const float*)d_in[7];
  const float* b3  = (const float*)d_in[8];
  const float* Wl  = (const float*)d_in[9];
  const float* bl  = (const float*)d_in[10];
  float* out = (float*)d_out;

  const int n = in_sizes[0];
  const int E = in_sizes[1] / 2;
  const int* rowv = ei;            // edge_index[0] : message source
  const int* colv = ei + E;        // edge_index[1] : aggregation destination

  char* w = (char*)d_ws;
  size_t o = 0;
  auto alloc = [&](size_t bytes) {
    size_t r = (o + 255) & ~(size_t)255;
    o = r + bytes;
    return r;
  };
  // zero-init region (contiguous): deg, cursor, pooled, s
  size_t o_deg  = alloc((size_t)n * 4);
  size_t o_cur  = alloc((size_t)n * 4);
  size_t o_pool = alloc((size_t)NGRAPH * HDIM * 4);
  size_t o_s    = alloc((size_t)n * 4);
  size_t zero_end = o;
  size_t o_off  = alloc(((size_t)n + 1) * 4);
  size_t o_ts   = alloc(256 * 4);
  size_t o_dinv = alloc((size_t)n * 4);
  size_t o_t1   = alloc((size_t)NGRAPH * HDIM * 4);
  size_t o_wt   = alloc((size_t)HDIM * HDIM * 4);
  size_t o_gw   = alloc((size_t)E * 8);
  size_t o_bufA = alloc((size_t)n * HDIM * 4);
  size_t o_bufB = alloc((size_t)n * HDIM * 4);
  (void)ws_size; (void)n_in; (void)out_size;

  int*   deg    = (int*)(w + o_deg);
  int*   cursor = (int*)(w + o_cur);
  float* pooled = (float*)(w + o_pool);
  float* s      = (float*)(w + o_s);
  int*   off    = (int*)(w + o_off);
  int*   ts     = (int*)(w + o_ts);
  float* dinv   = (float*)(w + o_dinv);
  float* t1     = (float*)(w + o_t1);
  float* W2T    = (float*)(w + o_wt);
  int2*  gw     = (int2*)(w + o_gw);
  float* bufA   = (float*)(w + o_bufA);  // h2 (gemm out)
  float* bufB   = (float*)(w + o_bufB);  // gemm in (z); later P + partials
  float* P        = bufB;                                    // 25.6 MB
  float* partials = (float*)((char*)bufB + (size_t)n * NGRAPH * 4);

  hipMemsetAsync(w + o_deg, 0, zero_end - o_deg, stream);
  k_wtr<<<64, 256, 0, stream>>>(W2, W2T);  // no deps; overlaps setup

  const int nTiles = (n + 1023) / 1024;
  k_count<<<(E + 255) / 256, 256, 0, stream>>>(colv, E, deg);
  k_scan1<<<nTiles, 256, 0, stream>>>(deg, n, off, ts, dinv);
  k_scan2<<<1, 128, 0, stream>>>(ts, nTiles);
  k_scan3<<<(n + 255) / 256, 256, 0, stream>>>(off, ts, n, E);

  // fused: CSR build + layer-1 scalar aggregation (s)
  k_edge<<<(E + n + 255) / 256, 256, 0, stream>>>(rowv, colv, E, off, cursor, dinv, x, s,
                                                  gw, n);

  // fused rank-1 h1 + relu + layer-2 aggregation -> z (bufB)
  k_l2in<<<(n + 3) / 4, 256, 0, stream>>>(s, off, gw, dinv, W1, b1, (float2*)bufB, n);

  // layer 2 GEMM (+bias+relu): bufB @ W2 -> bufA
  k_gemm<<<(n + 127) / 128, 256, 0, stream>>>(bufB, W2T, b2, bufA, n);

  // layer 3 + pool: pooled = P^T * h2 (bufB dead after gemm; reuse for P/partials)
  hipMemsetAsync(P, 0, (size_t)n * NGRAPH * 4, stream);
  k_pbuild<<<(E + n + 255) / 256, 256, 0, stream>>>(rowv, colv, E, dinv, bat, P, n);
  const int nPB = (n + PG_NODES - 1) / PG_NODES;
  k_pgemm<<<nPB, 256, 0, stream>>>(bufA, P, partials, n);
  k_reduce<<<dim3(32, 8), 256, 0, stream>>>(partials, pooled, nPB);

  k_mid<<<NGRAPH, HDIM, 0, stream>>>(pooled, bat, n, W3, b3, t1);
  k_out<<<1, 512, 0, stream>>>(t1, Wl, bl, out);
}